// Round 9
// baseline (85.127 us; speedup 1.0000x reference)
//
#include <hip/hip_runtime.h>

// Problem constants (reference: B=8, N=4096, F=1024, C=64)
#define B_   8
#define N_   4096
#define F_   1024
#define C_   64
#define ROWS 64        // rows per block
#define KC   32        // K (f) floats per chunk
#define NT   (F_ / KC) // 32 chunks
#define NBLK (N_ / ROWS) // 64 row-blocks per (inp,b)
#define MARGIN 0.08f   // hi-only bf16 score error sigma ~6e-3; 0.08 ~ 10 sigma on diffs

typedef __attribute__((ext_vector_type(8))) short bhalf8;   // 8 bf16 (MFMA A/B frag)
typedef __attribute__((ext_vector_type(4))) float f32x4;    // MFMA C/D frag
typedef __attribute__((ext_vector_type(4))) unsigned short us4;

__device__ __forceinline__ unsigned short f2bf_rne(float x) {
    unsigned u = __builtin_bit_cast(unsigned, x);
    u += 0x7fffu + ((u >> 16) & 1u);          // round-to-nearest-even
    return (unsigned short)(u >> 16);
}
__device__ __forceinline__ bhalf8 cvt8(float4 a, float4 b) {
    bhalf8 r;
    r[0] = (short)f2bf_rne(a.x); r[1] = (short)f2bf_rne(a.y);
    r[2] = (short)f2bf_rne(a.z); r[3] = (short)f2bf_rne(a.w);
    r[4] = (short)f2bf_rne(b.x); r[5] = (short)f2bf_rne(b.y);
    r[6] = (short)f2bf_rne(b.z); r[7] = (short)f2bf_rne(b.w);
    return r;
}
// Direct global->LDS (no VGPR round-trip). LDS dest is wave-uniform base;
// HW scatters lane*16B. Global src IS per-lane (carries the pre-swizzle).
__device__ __forceinline__ void load_lds16(const void* g, void* l) {
    __builtin_amdgcn_global_load_lds(
        (const __attribute__((address_space(1))) unsigned int*)g,
        (__attribute__((address_space(3))) unsigned int*)l, 16, 0, 0);
}

#define LEXGT(a, ai, b, bi) ((a) > (b) || ((a) == (b) && (ai) < (bi)))
#define INSERT3(vv, nn)                                                        \
    do {                                                                       \
        float _v = (vv); int _n = (nn);                                        \
        if (LEXGT(_v, _n, v0, i0)) { v2=v1; i2=i1; v1=v0; i1=i0; v0=_v; i0=_n; } \
        else if (LEXGT(_v, _n, v1, i1)) { v2=v1; i2=i1; v1=_v; i1=_n; }        \
        else if (LEXGT(_v, _n, v2, i2)) { v2=_v; i2=_n; }                      \
    } while (0)

// K0: convert W (fp32 [64][1024]) to bf16 (hi only) in workspace.
__global__ __launch_bounds__(256) void wconv_kernel(
    const float* __restrict__ W, unsigned short* __restrict__ Wh)
{
    int i = blockIdx.x * 256 + threadIdx.x;        // 16384 float4s total
    float4 v = ((const float4*)W)[i];
    us4 hh;
    hh[0] = f2bf_rne(v.x); hh[1] = f2bf_rne(v.y);
    hh[2] = f2bf_rne(v.z); hh[3] = f2bf_rne(v.w);
    ((us4*)Wh)[i] = hh;
}

// K1: hi-only bf16 MFMA scores. 4 LDS buffers, 2-deep global_load_lds
// prefetch, counted vmcnt(6), ONE s_barrier per chunk. NBUF=4 proof:
// stage(t+2) overwrites the buffer read at C(t-2); C(t-2) precedes
// barrier(t-1) (program order within iter t-2..t-1), S(t+2) follows
// barrier(t-1) -> no post-compute barrier needed.
// 256 thr = 4 waves, 64 rows x 64 classes, 48 KiB LDS -> 3 blocks/CU.
__global__ __launch_bounds__(256, 4) void score_top_kernel(
    const float* __restrict__ x1, const float* __restrict__ x2,
    const unsigned short* __restrict__ Wh,
    float* __restrict__ pv, int* __restrict__ pi)
{
    __shared__ __align__(16) char lds[49152];   // X: [4][64][128B] @0; W: [4][64][64B] @32768

    const int tid  = threadIdx.x;
    const int nb   = blockIdx.x;   // 0..63 (64-row group)
    const int b    = blockIdx.y;   // 0..7
    const int inp  = blockIdx.z;   // 0..1
    const float* __restrict__ x = inp ? x2 : x1;
    const float* __restrict__ xbase = x + ((size_t)b * N_ + (size_t)nb * ROWS) * F_;

    const int lane = tid & 63;
    const int w    = tid >> 6;       // wave 0..3 = m-tile
    const int rsel = lane & 15;
    const int g    = lane >> 4;      // 0..3

#define XOFF(buf) ((buf) * 8192)
#define WOFF(buf) (32768 + (buf) * 4096)

#define STAGE(t, buf)                                                          \
    do {                                                                       \
        const int f0_ = (t) * KC;                                              \
        _Pragma("unroll")                                                      \
        for (int j = 0; j < 2; ++j) {                                          \
            int ii = w * 2 + j;                                                \
            int r  = ii * 8 + (lane >> 3);                                     \
            int cg = (lane & 7) ^ (r & 7);                                     \
            load_lds16(xbase + (size_t)r * F_ + f0_ + cg * 4,                  \
                       lds + XOFF(buf) + ii * 1024);                           \
        }                                                                      \
        {                                                                      \
            int cls = w * 16 + (lane >> 2);                                    \
            int cg  = (lane & 3) ^ ((cls >> 1) & 3);                           \
            load_lds16(Wh + (size_t)cls * F_ + f0_ + cg * 8,                   \
                       lds + WOFF(buf) + w * 1024);                            \
        }                                                                      \
        __builtin_amdgcn_sched_barrier(0);                                     \
    } while (0)

#define COMPUTE(buf)                                                           \
    do {                                                                       \
        const char* xb = lds + XOFF(buf);                                      \
        const char* wb = lds + WOFF(buf);                                      \
        float4 xlo = *(const float4*)(xb + r_ * 128 + aswz0);                  \
        float4 xhi = *(const float4*)(xb + r_ * 128 + aswz1);                  \
        bhalf8 ah = cvt8(xlo, xhi);                                            \
        _Pragma("unroll")                                                      \
        for (int nt = 0; nt < 4; ++nt) {                                       \
            int cls = nt * 16 + rsel;                                          \
            bhalf8 bf = *(const bhalf8*)(wb + cls * 64 + ((g ^ ((cls >> 1) & 3)) * 16)); \
            acc[nt] = __builtin_amdgcn_mfma_f32_16x16x32_bf16(ah, bf, acc[nt], 0, 0, 0); \
        }                                                                      \
    } while (0)

    f32x4 acc[4];
    #pragma unroll
    for (int nt = 0; nt < 4; ++nt) acc[nt] = (f32x4){0.f, 0.f, 0.f, 0.f};

    const int r_    = w * 16 + rsel;          // local A row
    const int aswz0 = ((2 * g)     ^ (r_ & 7)) * 16;
    const int aswz1 = ((2 * g + 1) ^ (r_ & 7)) * 16;

    STAGE(0, 0);
    STAGE(1, 1);

    for (int t = 0; t < NT - 2; ++t) {
        STAGE(t + 2, (t + 2) & 3);
        asm volatile("s_waitcnt vmcnt(6)" ::: "memory");  // stage(t) done; t+1,t+2 in flight
        __builtin_amdgcn_sched_barrier(0);
        __builtin_amdgcn_s_barrier();                     // all waves' stage(t) complete
        COMPUTE(t & 3);
        __builtin_amdgcn_sched_barrier(0);
    }
    asm volatile("s_waitcnt vmcnt(3)" ::: "memory");
    __builtin_amdgcn_sched_barrier(0);
    __builtin_amdgcn_s_barrier();
    COMPUTE((NT - 2) & 3);
    __builtin_amdgcn_sched_barrier(0);
    asm volatile("s_waitcnt vmcnt(0)" ::: "memory");
    __builtin_amdgcn_sched_barrier(0);
    __builtin_amdgcn_s_barrier();
    COMPUTE((NT - 1) & 3);

    // ---- per-wave top-3 per class. D layout: col=lane&15 (class), row=4g+r.
    float wv0[4], wv1[4], wv2[4]; int wi0[4], wi1[4], wi2[4];
    #pragma unroll
    for (int nt = 0; nt < 4; ++nt) {
        float v0 = -3.4e38f, v1 = -3.4e38f, v2 = -3.4e38f;
        int   i0 = 0x7fffffff, i1 = 0x7fffffff, i2 = 0x7fffffff;
        #pragma unroll
        for (int r = 0; r < 4; ++r) {
            int n = nb * ROWS + w * 16 + 4 * g + r;
            INSERT3(acc[nt][r], n);
        }
        #pragma unroll
        for (int d = 16; d <= 32; d <<= 1) {
            float u0 = __shfl_xor(v0, d), u1 = __shfl_xor(v1, d), u2 = __shfl_xor(v2, d);
            int   j0 = __shfl_xor(i0, d), j1 = __shfl_xor(i1, d), j2 = __shfl_xor(i2, d);
            INSERT3(u0, j0); INSERT3(u1, j1); INSERT3(u2, j2);
        }
        wv0[nt] = v0; wv1[nt] = v1; wv2[nt] = v2;
        wi0[nt] = i0; wi1[nt] = i1; wi2[nt] = i2;
    }

    __syncthreads();                 // safe to alias LDS now
    float* tv = (float*)lds;                   // [4][64][3] = 3 KiB
    int*   ti = (int*)(lds + 8192);            // [4][64][3] = 3 KiB
    if (lane < 16) {
        #pragma unroll
        for (int nt = 0; nt < 4; ++nt) {
            int c = nt * 16 + lane;
            tv[(w * C_ + c) * 3 + 0] = wv0[nt]; ti[(w * C_ + c) * 3 + 0] = wi0[nt];
            tv[(w * C_ + c) * 3 + 1] = wv1[nt]; ti[(w * C_ + c) * 3 + 1] = wi1[nt];
            tv[(w * C_ + c) * 3 + 2] = wv2[nt]; ti[(w * C_ + c) * 3 + 2] = wi2[nt];
        }
    }
    __syncthreads();

    // ---- block top-3 per class over 4 waves x 3, write partials
    if (tid < C_) {
        int c = tid;
        float v0 = -3.4e38f, v1 = -3.4e38f, v2 = -3.4e38f;
        int   i0 = 0x7fffffff, i1 = 0x7fffffff, i2 = 0x7fffffff;
        #pragma unroll
        for (int ww = 0; ww < 4; ++ww)
            #pragma unroll
            for (int k = 0; k < 3; ++k)
                INSERT3(tv[(ww * C_ + c) * 3 + k], ti[(ww * C_ + c) * 3 + k]);
        int blk = ((inp * B_ + b) * NBLK + nb);
        pv[(blk * C_ + c) * 3 + 0] = v0; pi[(blk * C_ + c) * 3 + 0] = i0;
        pv[(blk * C_ + c) * 3 + 1] = v1; pi[(blk * C_ + c) * 3 + 1] = i1;
        pv[(blk * C_ + c) * 3 + 2] = v2; pi[(blk * C_ + c) * 3 + 2] = i2;
    }
}

// K2: ONE WAVE per (inp,b,c). lane = row-block (64), each holds its top-3.
// Ballot-collect candidates within MARGIN of global max; exact fp32 dot
// rescue if >1 (lex tie-break: score desc, index asc); gather winning row.
__global__ __launch_bounds__(64) void select_gather_kernel(
    const float* __restrict__ x1, const float* __restrict__ x2,
    const float* __restrict__ W,
    const float* __restrict__ pv, const int* __restrict__ pi,
    float* __restrict__ out)
{
    const int c    = blockIdx.x;    // 0..63
    const int b    = blockIdx.y;    // 0..7
    const int inp  = blockIdx.z;    // 0..1
    const int lane = threadIdx.x;   // 0..63 = row-block

    const int blk  = ((inp * B_ + b) * NBLK + lane);
    const int base = (blk * C_ + c) * 3;
    const float v0 = pv[base + 0], v1 = pv[base + 1], v2 = pv[base + 2];
    const int   j0 = pi[base + 0], j1 = pi[base + 1], j2 = pi[base + 2];

    float m = v0;                       // entries sorted: v0 is block max
    #pragma unroll
    for (int d = 32; d; d >>= 1) m = fmaxf(m, __shfl_xor(m, d));
    const float thr = m - MARGIN;

    int cand[8]; int nc = 0;
    #pragma unroll
    for (int k = 0; k < 3; ++k) {
        float vk = k == 0 ? v0 : (k == 1 ? v1 : v2);
        int   jk = k == 0 ? j0 : (k == 1 ? j1 : j2);
        unsigned long long mask = __ballot(vk >= thr);
        while (mask) {
            int l = __ffsll(mask) - 1; mask &= mask - 1;
            int n = __shfl(jk, l);
            if (nc < 8) cand[nc++] = n;
        }
    }

    const float* __restrict__ x = inp ? x2 : x1;
    int winner;
    if (nc == 1) {
        winner = cand[0];
    } else {
        float bv = -3.4e38f; int bn = 0x7fffffff;
        const float4* wrow = (const float4*)(W + (size_t)c * F_) + lane * 4;
        for (int k = 0; k < nc; ++k) {
            int n = cand[k];
            const float4* xrow = (const float4*)(x + ((size_t)b * N_ + n) * F_) + lane * 4;
            float p = 0.f;
            #pragma unroll
            for (int q = 0; q < 4; ++q) {
                float4 xv = xrow[q], wq = wrow[q];
                p += xv.x * wq.x + xv.y * wq.y + xv.z * wq.z + xv.w * wq.w;
            }
            #pragma unroll
            for (int d = 32; d; d >>= 1) p += __shfl_xor(p, d);   // all lanes get sum
            if (p > bv || (p == bv && n < bn)) { bv = p; bn = n; }
        }
        winner = bn;
    }

    const float4* src = (const float4*)(x + ((size_t)b * N_ + winner) * F_);
    float4* dst = (float4*)(out + (((size_t)inp * B_ + b) * C_ + c) * F_);
    #pragma unroll
    for (int q = 0; q < 4; ++q) dst[lane + 64 * q] = src[lane + 64 * q];
}

extern "C" void kernel_launch(void* const* d_in, const int* in_sizes, int n_in,
                              void* d_out, int out_size, void* d_ws, size_t ws_size,
                              hipStream_t stream) {
    const float* x1 = (const float*)d_in[0];
    const float* x2 = (const float*)d_in[1];
    const float* W  = (const float*)d_in[2];
    // d_in[3] (bias) is constant per class -> cannot change the argmax. Skipped.

    // ws: Wh bf16 [64][1024] = 128 KiB | pv [1024][64][3] f32 = 768 KiB | pi = 768 KiB
    unsigned short* Wh = (unsigned short*)d_ws;
    float* pv = (float*)((char*)d_ws + (size_t)C_ * F_ * sizeof(unsigned short));
    int*   pi = (int*)((char*)pv + (size_t)2 * B_ * NBLK * C_ * 3 * sizeof(float));

    wconv_kernel<<<C_ * F_ / 1024, 256, 0, stream>>>(W, Wh);
    dim3 g1(NBLK, B_, 2);
    score_top_kernel<<<g1, 256, 0, stream>>>(x1, x2, Wh, pv, pi);
    dim3 g2(C_, B_, 2);
    select_gather_kernel<<<g2, 64, 0, stream>>>(x1, x2, W, pv, pi, (float*)d_out);
}

// Round 10
// 73.233 us; speedup vs baseline: 1.1624x; 1.1624x over previous
//
#include <hip/hip_runtime.h>

// Problem constants (reference: B=8, N=4096, F=1024, C=64)
#define B_   8
#define N_   4096
#define F_   1024
#define C_   64
#define NBLK 16        // row-groups of 256 per (inp,b)
#define MARGIN 0.08f   // hi-only bf16 score error sigma ~6e-3; 0.08 ~ 10 sigma on diffs

typedef __attribute__((ext_vector_type(8))) short bhalf8;   // 8 bf16 (MFMA A/B frag)
typedef __attribute__((ext_vector_type(4))) float f32x4;    // MFMA C/D frag
typedef __attribute__((ext_vector_type(4))) unsigned short us4;

__device__ __forceinline__ unsigned short f2bf_rne(float x) {
    unsigned u = __builtin_bit_cast(unsigned, x);
    u += 0x7fffu + ((u >> 16) & 1u);          // round-to-nearest-even
    return (unsigned short)(u >> 16);
}
__device__ __forceinline__ bhalf8 cvt8(float4 a, float4 b) {
    bhalf8 r;
    r[0] = (short)f2bf_rne(a.x); r[1] = (short)f2bf_rne(a.y);
    r[2] = (short)f2bf_rne(a.z); r[3] = (short)f2bf_rne(a.w);
    r[4] = (short)f2bf_rne(b.x); r[5] = (short)f2bf_rne(b.y);
    r[6] = (short)f2bf_rne(b.z); r[7] = (short)f2bf_rne(b.w);
    return r;
}

#define LEXGT(a, ai, b, bi) ((a) > (b) || ((a) == (b) && (ai) < (bi)))
#define INSERT3(vv, nn)                                                        \
    do {                                                                       \
        float _v = (vv); int _n = (nn);                                        \
        if (LEXGT(_v, _n, v0, i0)) { v2=v1; i2=i1; v1=v0; i1=i0; v0=_v; i0=_n; } \
        else if (LEXGT(_v, _n, v1, i1)) { v2=v1; i2=i1; v1=_v; i1=_n; }        \
        else if (LEXGT(_v, _n, v2, i2)) { v2=_v; i2=_n; }                      \
    } while (0)
#define INSERT4(vv, nn)                                                        \
    do {                                                                       \
        float _v = (vv); int _n = (nn);                                        \
        if (LEXGT(_v, _n, v0, i0)) { v3=v2; i3=i2; v2=v1; i2=i1; v1=v0; i1=i0; v0=_v; i0=_n; } \
        else if (LEXGT(_v, _n, v1, i1)) { v3=v2; i3=i2; v2=v1; i2=i1; v1=_v; i1=_n; } \
        else if (LEXGT(_v, _n, v2, i2)) { v3=v2; i3=i2; v2=_v; i2=_n; }        \
        else if (LEXGT(_v, _n, v3, i3)) { v3=_v; i3=_n; }                      \
    } while (0)

// K0: convert W (fp32 [64][1024]) to bf16 (hi only) in workspace.
__global__ __launch_bounds__(256) void wconv_kernel(
    const float* __restrict__ W, unsigned short* __restrict__ Wh)
{
    int i = blockIdx.x * 256 + threadIdx.x;        // 16384 float4s total
    float4 v = ((const float4*)W)[i];
    us4 hh;
    hh[0] = f2bf_rne(v.x); hh[1] = f2bf_rne(v.y);
    hh[2] = f2bf_rne(v.z); hh[3] = f2bf_rne(v.w);
    ((us4*)Wh)[i] = hh;
}

// K1: hi-only bf16 MFMA scores, barrier-free per-wave streaming.
// 1024 thr = 16 waves, grid 256 = 1 block/CU. Full W bf16 in 128 KiB LDS
// (staged once; no per-chunk W restage -> -128 MB L2 traffic vs R7-R9).
// X streamed global->reg with a HAND-PINNED register double buffer:
// volatile-asm global_load_dwordx4 groups + manual s_waitcnt vmcnt(8) +
// sched_barrier(0) fences (volatile asm is mutually ordered; the region
// {COMPUTE(t), ISSUE(t+2)} between WAITVs makes vmcnt(8) prove group t+1
// complete). 8 KB in flight per wave, no main-loop barriers.
__global__ __launch_bounds__(1024, 4) void score_top_kernel(
    const float* __restrict__ x1, const float* __restrict__ x2,
    const unsigned short* __restrict__ Wh,
    float* __restrict__ pv, int* __restrict__ pi)
{
    __shared__ __align__(16) char lds[131072];  // W bf16 [64][2048B] swizzled; reused for reduction

    const int tid  = threadIdx.x;
    const int nb   = blockIdx.x;   // 0..15 (256-row group)
    const int b    = blockIdx.y;   // 0..7
    const int inp  = blockIdx.z;   // 0..1
    const float* __restrict__ x = inp ? x2 : x1;

    const int lane = tid & 63;
    const int w    = tid >> 6;       // wave 0..15
    const int rsel = lane & 15;
    const int g    = lane >> 4;      // 0..3
    const int swz  = (rsel & 7) << 4;

    const int row = nb * 256 + w * 16 + rsel;
    const float* __restrict__ xr = x + ((size_t)b * N_ + row) * F_ + g * 8;

    f32x4 acc[4];
    #pragma unroll
    for (int nt = 0; nt < 4; ++nt) acc[nt] = (f32x4){0.f, 0.f, 0.f, 0.f};

// 8 x 16B per wave per chunk (KC=128 floats of this lane's row slice).
// Byte offsets within the chunk: st*128 + {0,16}, st=0..3.
#define ISSUE(buf, t)                                                          \
    do {                                                                       \
        const float* a_ = xr + (t) * 128;                                      \
        asm volatile(                                                          \
            "global_load_dwordx4 %0, %8, off\n\t"                              \
            "global_load_dwordx4 %1, %8, off offset:16\n\t"                    \
            "global_load_dwordx4 %2, %8, off offset:128\n\t"                   \
            "global_load_dwordx4 %3, %8, off offset:144\n\t"                   \
            "global_load_dwordx4 %4, %8, off offset:256\n\t"                   \
            "global_load_dwordx4 %5, %8, off offset:272\n\t"                   \
            "global_load_dwordx4 %6, %8, off offset:384\n\t"                   \
            "global_load_dwordx4 %7, %8, off offset:400"                       \
            : "=v"(buf[0]), "=v"(buf[1]), "=v"(buf[2]), "=v"(buf[3]),          \
              "=v"(buf[4]), "=v"(buf[5]), "=v"(buf[6]), "=v"(buf[7])           \
            : "v"(a_));                                                        \
        __builtin_amdgcn_sched_barrier(0);                                     \
    } while (0)

#define WAITV(n)                                                               \
    do {                                                                       \
        asm volatile("s_waitcnt vmcnt(" #n ")" ::: "memory");                  \
        __builtin_amdgcn_sched_barrier(0);                                     \
    } while (0)

#define COMPUTE(src, kc)                                                       \
    do {                                                                       \
        _Pragma("unroll")                                                      \
        for (int st = 0; st < 4; ++st) {                                       \
            bhalf8 ah = cvt8(src[2 * st], src[2 * st + 1]);                    \
            int kb = (kc) * 256 + st * 64 + g * 16;                            \
            _Pragma("unroll")                                                  \
            for (int nt = 0; nt < 4; ++nt) {                                   \
                int cls = nt * 16 + rsel;                                      \
                bhalf8 bf = *(const bhalf8*)(lds + ((cls * 2048 + kb) ^ swz)); \
                acc[nt] = __builtin_amdgcn_mfma_f32_16x16x32_bf16(ah, bf, acc[nt], 0, 0, 0); \
            }                                                                  \
        }                                                                      \
    } while (0)

    float4 xa[8], xb[8];
    ISSUE(xa, 0);                                // start the X stream first

    // ---- stage full W bf16 -> LDS (once). 8192 x 16B, 8 per thread.
    #pragma unroll
    for (int j = 0; j < 8; ++j) {
        int gi = tid + 1024 * j;
        int c = gi >> 7, kq = gi & 127;
        bhalf8 v = *(const bhalf8*)(Wh + (size_t)c * F_ + kq * 8);
        *(bhalf8*)(lds + ((c * 2048 + kq * 16) ^ ((c & 7) << 4))) = v;
    }
    __syncthreads();

    ISSUE(xb, 1);
    WAITV(8);  COMPUTE(xa, 0);  ISSUE(xa, 2);
    WAITV(8);  COMPUTE(xb, 1);  ISSUE(xb, 3);
    WAITV(8);  COMPUTE(xa, 2);  ISSUE(xa, 4);
    WAITV(8);  COMPUTE(xb, 3);  ISSUE(xb, 5);
    WAITV(8);  COMPUTE(xa, 4);  ISSUE(xa, 6);
    WAITV(8);  COMPUTE(xb, 5);  ISSUE(xb, 7);
    WAITV(8);  COMPUTE(xa, 6);
    WAITV(0);  COMPUTE(xb, 7);

    // ---- per-wave top-3 per class. D layout: col=lane&15 (class), row=4g+r.
    float wv0[4], wv1[4], wv2[4]; int wi0[4], wi1[4], wi2[4];
    #pragma unroll
    for (int nt = 0; nt < 4; ++nt) {
        float v0 = -3.4e38f, v1 = -3.4e38f, v2 = -3.4e38f;
        int   i0 = 0x7fffffff, i1 = 0x7fffffff, i2 = 0x7fffffff;
        #pragma unroll
        for (int r = 0; r < 4; ++r) {
            int n = nb * 256 + w * 16 + 4 * g + r;
            INSERT3(acc[nt][r], n);
        }
        #pragma unroll
        for (int d = 16; d <= 32; d <<= 1) {
            float u0 = __shfl_xor(v0, d), u1 = __shfl_xor(v1, d), u2 = __shfl_xor(v2, d);
            int   j0 = __shfl_xor(i0, d), j1 = __shfl_xor(i1, d), j2 = __shfl_xor(i2, d);
            INSERT3(u0, j0); INSERT3(u1, j1); INSERT3(u2, j2);
        }
        wv0[nt] = v0; wv1[nt] = v1; wv2[nt] = v2;
        wi0[nt] = i0; wi1[nt] = i1; wi2[nt] = i2;
    }

    __syncthreads();                 // all waves done reading W -> safe to alias LDS
    float* tv = (float*)lds;                   // [16][64][3] = 12 KiB
    int*   ti = (int*)(lds + 16384);           // [16][64][3] = 12 KiB
    if (lane < 16) {
        #pragma unroll
        for (int nt = 0; nt < 4; ++nt) {
            int c = nt * 16 + lane;
            tv[(w * C_ + c) * 3 + 0] = wv0[nt]; ti[(w * C_ + c) * 3 + 0] = wi0[nt];
            tv[(w * C_ + c) * 3 + 1] = wv1[nt]; ti[(w * C_ + c) * 3 + 1] = wi1[nt];
            tv[(w * C_ + c) * 3 + 2] = wv2[nt]; ti[(w * C_ + c) * 3 + 2] = wi2[nt];
        }
    }
    __syncthreads();

    // ---- block top-4 per class over 16 waves x 3, write partials
    if (tid < C_) {
        int c = tid;
        float v0 = -3.4e38f, v1 = -3.4e38f, v2 = -3.4e38f, v3 = -3.4e38f;
        int   i0 = 0x7fffffff, i1 = 0x7fffffff, i2 = 0x7fffffff, i3 = 0x7fffffff;
        #pragma unroll 4
        for (int ww = 0; ww < 16; ++ww)
            #pragma unroll
            for (int k = 0; k < 3; ++k)
                INSERT4(tv[(ww * C_ + c) * 3 + k], ti[(ww * C_ + c) * 3 + k]);
        int blk = ((inp * B_ + b) * NBLK + nb);
        pv[(blk * C_ + c) * 4 + 0] = v0; pi[(blk * C_ + c) * 4 + 0] = i0;
        pv[(blk * C_ + c) * 4 + 1] = v1; pi[(blk * C_ + c) * 4 + 1] = i1;
        pv[(blk * C_ + c) * 4 + 2] = v2; pi[(blk * C_ + c) * 4 + 2] = i2;
        pv[(blk * C_ + c) * 4 + 3] = v3; pi[(blk * C_ + c) * 4 + 3] = i3;
    }
}

// K2: ONE WAVE per (inp,b,c). 64 entries (16 blocks x top-4): ballot-collect
// candidates within MARGIN of max; exact fp32 dot rescue if >1 (lex
// tie-break: score desc, index asc); gather winning row.
__global__ __launch_bounds__(64) void select_gather_kernel(
    const float* __restrict__ x1, const float* __restrict__ x2,
    const float* __restrict__ W,
    const float* __restrict__ pv, const int* __restrict__ pi,
    float* __restrict__ out)
{
    const int c    = blockIdx.x;    // 0..63
    const int b    = blockIdx.y;    // 0..7
    const int inp  = blockIdx.z;    // 0..1
    const int lane = threadIdx.x;   // 0..63

    const int nbk = lane >> 2, k = lane & 3;
    const int blk = ((inp * B_ + b) * NBLK + nbk);
    const int off = (blk * C_ + c) * 4 + k;
    const float v = pv[off];
    const int  id = pi[off];

    float m = v;
    #pragma unroll
    for (int d = 32; d; d >>= 1) m = fmaxf(m, __shfl_xor(m, d));
    const float thr = m - MARGIN;

    unsigned long long mask = __ballot(v >= thr);
    int cand[8]; int nc = 0;
    while (mask) {
        int l = __ffsll(mask) - 1; mask &= mask - 1;
        int n = __shfl(id, l);
        if (nc < 8) cand[nc++] = n;
    }

    const float* __restrict__ x = inp ? x2 : x1;
    int winner;
    if (nc == 1) {
        winner = cand[0];
    } else {
        float bv = -3.4e38f; int bn = 0x7fffffff;
        const float4* wrow = (const float4*)(W + (size_t)c * F_) + lane * 4;
        for (int kk = 0; kk < nc; ++kk) {
            int n = cand[kk];
            const float4* xrow = (const float4*)(x + ((size_t)b * N_ + n) * F_) + lane * 4;
            float p = 0.f;
            #pragma unroll
            for (int q = 0; q < 4; ++q) {
                float4 xv = xrow[q], wq = wrow[q];
                p += xv.x * wq.x + xv.y * wq.y + xv.z * wq.z + xv.w * wq.w;
            }
            #pragma unroll
            for (int d = 32; d; d >>= 1) p += __shfl_xor(p, d);   // all lanes get sum
            if (p > bv || (p == bv && n < bn)) { bv = p; bn = n; }
        }
        winner = bn;
    }

    const float4* src = (const float4*)(x + ((size_t)b * N_ + winner) * F_);
    float4* dst = (float4*)(out + (((size_t)inp * B_ + b) * C_ + c) * F_);
    #pragma unroll
    for (int q = 0; q < 4; ++q) dst[lane + 64 * q] = src[lane + 64 * q];
}

extern "C" void kernel_launch(void* const* d_in, const int* in_sizes, int n_in,
                              void* d_out, int out_size, void* d_ws, size_t ws_size,
                              hipStream_t stream) {
    const float* x1 = (const float*)d_in[0];
    const float* x2 = (const float*)d_in[1];
    const float* W  = (const float*)d_in[2];
    // d_in[3] (bias) is constant per class -> cannot change the argmax. Skipped.

    // ws: Wh bf16 [64][1024] = 128 KiB | pv [256][64][4] f32 = 128 KiB | pi = 128 KiB
    unsigned short* Wh = (unsigned short*)d_ws;
    float* pv = (float*)((char*)d_ws + (size_t)C_ * F_ * sizeof(unsigned short));
    int*   pi = (int*)((char*)pv + (size_t)2 * B_ * NBLK * C_ * 4 * sizeof(float));

    wconv_kernel<<<C_ * F_ / 1024, 256, 0, stream>>>(W, Wh);
    dim3 g1(NBLK, B_, 2);
    score_top_kernel<<<g1, 1024, 0, stream>>>(x1, x2, Wh, pv, pi);
    dim3 g2(C_, B_, 2);
    select_gather_kernel<<<g2, 64, 0, stream>>>(x1, x2, W, pv, pi, (float*)d_out);
}

// Round 11
// 66.575 us; speedup vs baseline: 1.2787x; 1.1000x over previous
//
#include <hip/hip_runtime.h>

// Problem constants (reference: B=8, N=4096, F=1024, C=64)
#define B_   8
#define N_   4096
#define F_   1024
#define C_   64
#define ROWS 32          // rows per block
#define KC   32          // K (f) floats per chunk
#define NT   (F_ / KC)   // 32 chunks
#define NBLK (N_ / ROWS) // 128 row-blocks per (inp,b)
#define MARGIN 0.08f     // hi-only bf16 score error sigma ~6e-3; 0.08 ~ 10 sigma on diffs

typedef __attribute__((ext_vector_type(8))) short bhalf8;   // 8 bf16 (MFMA A/B frag)
typedef __attribute__((ext_vector_type(4))) float f32x4;    // MFMA C/D frag
typedef __attribute__((ext_vector_type(4))) unsigned short us4;

__device__ __forceinline__ unsigned short f2bf_rne(float x) {
    unsigned u = __builtin_bit_cast(unsigned, x);
    u += 0x7fffu + ((u >> 16) & 1u);          // round-to-nearest-even
    return (unsigned short)(u >> 16);
}
__device__ __forceinline__ bhalf8 cvt8(float4 a, float4 b) {
    bhalf8 r;
    r[0] = (short)f2bf_rne(a.x); r[1] = (short)f2bf_rne(a.y);
    r[2] = (short)f2bf_rne(a.z); r[3] = (short)f2bf_rne(a.w);
    r[4] = (short)f2bf_rne(b.x); r[5] = (short)f2bf_rne(b.y);
    r[6] = (short)f2bf_rne(b.z); r[7] = (short)f2bf_rne(b.w);
    return r;
}
// Direct global->LDS (no VGPR round-trip). LDS dest is wave-uniform base;
// HW scatters lane*16B. Global src IS per-lane (carries the pre-swizzle).
__device__ __forceinline__ void load_lds16(const void* g, void* l) {
    __builtin_amdgcn_global_load_lds(
        (const __attribute__((address_space(1))) unsigned int*)g,
        (__attribute__((address_space(3))) unsigned int*)l, 16, 0, 0);
}

#define LEXGT(a, ai, b, bi) ((a) > (b) || ((a) == (b) && (ai) < (bi)))
#define INSERT2(vv, nn)                                                        \
    do {                                                                       \
        float _v = (vv); int _n = (nn);                                        \
        if (LEXGT(_v, _n, v0, i0)) { v1=v0; i1=i0; v0=_v; i0=_n; }             \
        else if (LEXGT(_v, _n, v1, i1)) { v1=_v; i1=_n; }                      \
    } while (0)
#define INSERT3(vv, nn)                                                        \
    do {                                                                       \
        float _v = (vv); int _n = (nn);                                        \
        if (LEXGT(_v, _n, v0, i0)) { v2=v1; i2=i1; v1=v0; i1=i0; v0=_v; i0=_n; } \
        else if (LEXGT(_v, _n, v1, i1)) { v2=v1; i2=i1; v1=_v; i1=_n; }        \
        else if (LEXGT(_v, _n, v2, i2)) { v2=_v; i2=_n; }                      \
    } while (0)

// K0: convert W (fp32 [64][1024]) to bf16 (hi only) in workspace.
__global__ __launch_bounds__(256) void wconv_kernel(
    const float* __restrict__ W, unsigned short* __restrict__ Wh)
{
    int i = blockIdx.x * 256 + threadIdx.x;        // 16384 float4s total
    float4 v = ((const float4*)W)[i];
    us4 hh;
    hh[0] = f2bf_rne(v.x); hh[1] = f2bf_rne(v.y);
    hh[2] = f2bf_rne(v.z); hh[3] = f2bf_rne(v.w);
    ((us4*)Wh)[i] = hh;
}

// K1: hi-only bf16 MFMA scores. R7's proven 2-phase global_load_lds pipeline,
// halved block: 128 thr = 2 waves, 32 rows x 64 classes, 16 KiB LDS ->
// grid 2048 = 8 blocks/CU x 2 waves = 16 waves/CU. Cross-block stagger (the
// one mechanism that has moved real time) doubles vs R7. STAGE(t+1) issued
// before COMPUTE(t); one __syncthreads per chunk drains vmcnt.
__global__ __launch_bounds__(128, 4) void score_top_kernel(
    const float* __restrict__ x1, const float* __restrict__ x2,
    const unsigned short* __restrict__ Wh,
    float* __restrict__ pv, int* __restrict__ pi)
{
    __shared__ __align__(16) char lds[16384];   // X: [2][32][128B] @0; W: [2][64][64B] @8192

    const int tid  = threadIdx.x;
    const int nb   = blockIdx.x;   // 0..127 (32-row group)
    const int b    = blockIdx.y;   // 0..7
    const int inp  = blockIdx.z;   // 0..1
    const float* __restrict__ x = inp ? x2 : x1;
    const float* __restrict__ xbase = x + ((size_t)b * N_ + (size_t)nb * ROWS) * F_;

    const int lane = tid & 63;
    const int w    = tid >> 6;       // wave 0..1 = m-tile
    const int rsel = lane & 15;
    const int g    = lane >> 4;      // 0..3

#define XOFF(buf) ((buf) * 4096)
#define WOFF(buf) (8192 + (buf) * 4096)

#define STAGE(t, buf)                                                          \
    do {                                                                       \
        const int f0_ = (t) * KC;                                              \
        _Pragma("unroll")                                                      \
        for (int j = 0; j < 2; ++j) {                                          \
            int ii = w * 2 + j;                       /* 0..3: 8-row groups */ \
            int r  = ii * 8 + (lane >> 3);                                     \
            int cg = (lane & 7) ^ (r & 7);                                     \
            load_lds16(xbase + (size_t)r * F_ + f0_ + cg * 4,                  \
                       lds + XOFF(buf) + ii * 1024);                           \
        }                                                                      \
        _Pragma("unroll")                                                      \
        for (int j = 0; j < 2; ++j) {                                          \
            int wi  = w * 2 + j;                      /* 0..3: 16-cls groups */\
            int cls = wi * 16 + (lane >> 2);                                   \
            int cg  = (lane & 3) ^ ((cls >> 1) & 3);                           \
            load_lds16(Wh + (size_t)cls * F_ + f0_ + cg * 8,                   \
                       lds + WOFF(buf) + wi * 1024);                           \
        }                                                                      \
    } while (0)

#define COMPUTE(buf)                                                           \
    do {                                                                       \
        const char* xb = lds + XOFF(buf);                                      \
        const char* wb = lds + WOFF(buf);                                      \
        float4 xlo = *(const float4*)(xb + r_ * 128 + aswz0);                  \
        float4 xhi = *(const float4*)(xb + r_ * 128 + aswz1);                  \
        bhalf8 ah = cvt8(xlo, xhi);                                            \
        _Pragma("unroll")                                                      \
        for (int nt = 0; nt < 4; ++nt) {                                       \
            int cls = nt * 16 + rsel;                                          \
            bhalf8 bf = *(const bhalf8*)(wb + cls * 64 + ((g ^ ((cls >> 1) & 3)) * 16)); \
            acc[nt] = __builtin_amdgcn_mfma_f32_16x16x32_bf16(ah, bf, acc[nt], 0, 0, 0); \
        }                                                                      \
    } while (0)

    f32x4 acc[4];
    #pragma unroll
    for (int nt = 0; nt < 4; ++nt) acc[nt] = (f32x4){0.f, 0.f, 0.f, 0.f};

    const int r_    = w * 16 + rsel;          // local A row (0..31)
    const int aswz0 = ((2 * g)     ^ (r_ & 7)) * 16;
    const int aswz1 = ((2 * g + 1) ^ (r_ & 7)) * 16;

    STAGE(0, 0);
    __syncthreads();

    for (int t = 0; t < NT; ++t) {
        const int cur = t & 1;
        if (t + 1 < NT) STAGE(t + 1, cur ^ 1);
        COMPUTE(cur);
        __syncthreads();   // drains STAGE(t+1) vmcnt; protects buffer reuse
    }

    // ---- per-wave top-3 per class. D layout: col=lane&15 (class), row=4g+r.
    float wv0[4], wv1[4], wv2[4]; int wi0[4], wi1[4], wi2[4];
    #pragma unroll
    for (int nt = 0; nt < 4; ++nt) {
        float v0 = -3.4e38f, v1 = -3.4e38f, v2 = -3.4e38f;
        int   i0 = 0x7fffffff, i1 = 0x7fffffff, i2 = 0x7fffffff;
        #pragma unroll
        for (int r = 0; r < 4; ++r) {
            int n = nb * ROWS + w * 16 + 4 * g + r;
            INSERT3(acc[nt][r], n);
        }
        #pragma unroll
        for (int d = 16; d <= 32; d <<= 1) {
            float u0 = __shfl_xor(v0, d), u1 = __shfl_xor(v1, d), u2 = __shfl_xor(v2, d);
            int   j0 = __shfl_xor(i0, d), j1 = __shfl_xor(i1, d), j2 = __shfl_xor(i2, d);
            INSERT3(u0, j0); INSERT3(u1, j1); INSERT3(u2, j2);
        }
        wv0[nt] = v0; wv1[nt] = v1; wv2[nt] = v2;
        wi0[nt] = i0; wi1[nt] = i1; wi2[nt] = i2;
    }

    __syncthreads();                 // safe to alias LDS now
    float* tv = (float*)lds;                   // [2][64][3] floats
    int*   ti = (int*)(lds + 4096);            // [2][64][3] ints
    if (lane < 16) {
        #pragma unroll
        for (int nt = 0; nt < 4; ++nt) {
            int c = nt * 16 + lane;
            tv[(w * C_ + c) * 3 + 0] = wv0[nt]; ti[(w * C_ + c) * 3 + 0] = wi0[nt];
            tv[(w * C_ + c) * 3 + 1] = wv1[nt]; ti[(w * C_ + c) * 3 + 1] = wi1[nt];
            tv[(w * C_ + c) * 3 + 2] = wv2[nt]; ti[(w * C_ + c) * 3 + 2] = wi2[nt];
        }
    }
    __syncthreads();

    // ---- block top-2 per class over 2 waves x 3, write partials
    if (tid < C_) {
        int c = tid;
        float v0 = -3.4e38f, v1 = -3.4e38f;
        int   i0 = 0x7fffffff, i1 = 0x7fffffff;
        #pragma unroll
        for (int ww = 0; ww < 2; ++ww)
            #pragma unroll
            for (int k = 0; k < 3; ++k)
                INSERT2(tv[(ww * C_ + c) * 3 + k], ti[(ww * C_ + c) * 3 + k]);
        int blk = ((inp * B_ + b) * NBLK + nb);
        pv[(blk * C_ + c) * 2 + 0] = v0; pi[(blk * C_ + c) * 2 + 0] = i0;
        pv[(blk * C_ + c) * 2 + 1] = v1; pi[(blk * C_ + c) * 2 + 1] = i1;
    }
}

// K2: one block per (inp,b,c). 256 entries (128 blocks x top-2): collect
// candidates within MARGIN of max, exact fp32 dot rescue if >1, gather row.
__global__ __launch_bounds__(256) void select_gather_kernel(
    const float* __restrict__ x1, const float* __restrict__ x2,
    const float* __restrict__ W,
    const float* __restrict__ pv, const int* __restrict__ pi,
    float* __restrict__ out)
{
    const int c   = blockIdx.x;    // 0..63
    const int b   = blockIdx.y;    // 0..7
    const int inp = blockIdx.z;    // 0..1
    const int tid = threadIdx.x;

    __shared__ int   s_cnt;
    __shared__ float s_m[4];
    __shared__ int   s_cand[16];
    __shared__ float s_val[16];
    __shared__ float s_wsum[4];
    __shared__ int   s_win;

    if (tid == 0) s_cnt = 0;
    __syncthreads();

    const int nbk = tid >> 1, k = tid & 1;
    const int blk = ((inp * B_ + b) * NBLK + nbk);
    const int off = (blk * C_ + c) * 2 + k;
    const float v = pv[off];
    const int  id = pi[off];
    {
        float m = v;
        #pragma unroll
        for (int d = 32; d; d >>= 1) m = fmaxf(m, __shfl_xor(m, d));
        if ((tid & 63) == 0) s_m[tid >> 6] = m;
    }
    __syncthreads();
    const float m = fmaxf(fmaxf(s_m[0], s_m[1]), fmaxf(s_m[2], s_m[3]));
    if (v >= m - MARGIN) {
        int p = atomicAdd(&s_cnt, 1);
        if (p < 16) s_cand[p] = id;
    }
    __syncthreads();

    const float* __restrict__ x = inp ? x2 : x1;
    const int ncand = min(s_cnt, 16);
    int winner;
    if (ncand == 1) {
        winner = s_cand[0];
    } else {
        for (int k2 = 0; k2 < ncand; ++k2) {
            int n = s_cand[k2];
            float4 xv = *(const float4*)(x + ((size_t)b * N_ + n) * F_ + tid * 4);
            float4 wq = *(const float4*)(W + (size_t)c * F_ + tid * 4);
            float p = xv.x * wq.x + xv.y * wq.y + xv.z * wq.z + xv.w * wq.w;
            #pragma unroll
            for (int d = 32; d; d >>= 1) p += __shfl_down(p, d);
            if ((tid & 63) == 0) s_wsum[tid >> 6] = p;
            __syncthreads();
            if (tid == 0) s_val[k2] = s_wsum[0] + s_wsum[1] + s_wsum[2] + s_wsum[3];
            __syncthreads();
        }
        if (tid == 0) {
            float bv = s_val[0]; int bn = s_cand[0];
            for (int k2 = 1; k2 < ncand; ++k2)
                if (s_val[k2] > bv || (s_val[k2] == bv && s_cand[k2] < bn)) { bv = s_val[k2]; bn = s_cand[k2]; }
            s_win = bn;
        }
        __syncthreads();
        winner = s_win;
    }

    float4 vv = *(const float4*)(x + ((size_t)b * N_ + winner) * F_ + tid * 4);
    *(float4*)(out + (((size_t)inp * B_ + b) * C_ + c) * F_ + tid * 4) = vv;
}

extern "C" void kernel_launch(void* const* d_in, const int* in_sizes, int n_in,
                              void* d_out, int out_size, void* d_ws, size_t ws_size,
                              hipStream_t stream) {
    const float* x1 = (const float*)d_in[0];
    const float* x2 = (const float*)d_in[1];
    const float* W  = (const float*)d_in[2];
    // d_in[3] (bias) is constant per class -> cannot change the argmax. Skipped.

    // ws: Wh bf16 [64][1024] = 128 KiB | pv [2048][64][2] f32 = 1 MiB | pi = 1 MiB
    unsigned short* Wh = (unsigned short*)d_ws;
    float* pv = (float*)((char*)d_ws + (size_t)C_ * F_ * sizeof(unsigned short));
    int*   pi = (int*)((char*)pv + (size_t)2 * B_ * NBLK * C_ * 2 * sizeof(float));

    wconv_kernel<<<C_ * F_ / 1024, 256, 0, stream>>>(W, Wh);
    dim3 g1(NBLK, B_, 2);
    score_top_kernel<<<g1, 128, 0, stream>>>(x1, x2, Wh, pv, pi);
    dim3 g2(C_, B_, 2);
    select_gather_kernel<<<g2, 256, 0, stream>>>(x1, x2, W, pv, pi, (float*)d_out);
}

// Round 12
// 65.620 us; speedup vs baseline: 1.2973x; 1.0146x over previous
//
#include <hip/hip_runtime.h>

// Problem constants (reference: B=8, N=4096, F=1024, C=64)
#define B_   8
#define N_   4096
#define F_   1024
#define C_   64
#define ROWS 64        // rows per block
#define KC   32        // K (f) floats per chunk
#define NT   (F_ / KC) // 32 chunks
#define NBLK (N_ / ROWS) // 64 row-blocks per (inp,b)
#define MARGIN 0.08f   // hi-only bf16 score error sigma ~6e-3; 0.08 ~ 10 sigma on diffs

typedef __attribute__((ext_vector_type(8))) short bhalf8;   // 8 bf16 (MFMA A/B frag)
typedef __attribute__((ext_vector_type(4))) float f32x4;    // MFMA C/D frag
typedef __attribute__((ext_vector_type(4))) unsigned short us4;

__device__ __forceinline__ unsigned short f2bf_rne(float x) {
    unsigned u = __builtin_bit_cast(unsigned, x);
    u += 0x7fffu + ((u >> 16) & 1u);          // round-to-nearest-even
    return (unsigned short)(u >> 16);
}
__device__ __forceinline__ bhalf8 cvt8(float4 a, float4 b) {
    bhalf8 r;
    r[0] = (short)f2bf_rne(a.x); r[1] = (short)f2bf_rne(a.y);
    r[2] = (short)f2bf_rne(a.z); r[3] = (short)f2bf_rne(a.w);
    r[4] = (short)f2bf_rne(b.x); r[5] = (short)f2bf_rne(b.y);
    r[6] = (short)f2bf_rne(b.z); r[7] = (short)f2bf_rne(b.w);
    return r;
}
// Direct global->LDS (no VGPR round-trip). LDS dest is wave-uniform base;
// HW scatters lane*16B. Global src IS per-lane (carries the pre-swizzle).
__device__ __forceinline__ void load_lds16(const void* g, void* l) {
    __builtin_amdgcn_global_load_lds(
        (const __attribute__((address_space(1))) unsigned int*)g,
        (__attribute__((address_space(3))) unsigned int*)l, 16, 0, 0);
}

#define LEXGT(a, ai, b, bi) ((a) > (b) || ((a) == (b) && (ai) < (bi)))
#define INSERT3(vv, nn)                                                        \
    do {                                                                       \
        float _v = (vv); int _n = (nn);                                        \
        if (LEXGT(_v, _n, v0, i0)) { v2=v1; i2=i1; v1=v0; i1=i0; v0=_v; i0=_n; } \
        else if (LEXGT(_v, _n, v1, i1)) { v2=v1; i2=i1; v1=_v; i1=_n; }        \
        else if (LEXGT(_v, _n, v2, i2)) { v2=_v; i2=_n; }                      \
    } while (0)

// K0: convert W (fp32 [64][1024]) to bf16 (hi only) in workspace.
__global__ __launch_bounds__(256) void wconv_kernel(
    const float* __restrict__ W, unsigned short* __restrict__ Wh)
{
    int i = blockIdx.x * 256 + threadIdx.x;        // 16384 float4s total
    float4 v = ((const float4*)W)[i];
    us4 hh;
    hh[0] = f2bf_rne(v.x); hh[1] = f2bf_rne(v.y);
    hh[2] = f2bf_rne(v.z); hh[3] = f2bf_rne(v.w);
    ((us4*)Wh)[i] = hh;
}

// K1: hi-only bf16 MFMA scores, R7 2-phase global_load_lds pipeline +
// PER-BLOCK STAGGERED K-CHUNK START (t0 hash): concurrent blocks read 32
// different 128B k-column offsets instead of sweeping channels in lockstep.
// fp32 acc is order-invariant to ~1e-6 << MARGIN; rescue recompute is
// order-fixed. 256 thr = 4 waves, 64 rows x 64 classes, 24 KiB -> 4 blk/CU.
__global__ __launch_bounds__(256, 4) void score_top_kernel(
    const float* __restrict__ x1, const float* __restrict__ x2,
    const unsigned short* __restrict__ Wh,
    float* __restrict__ pv, int* __restrict__ pi)
{
    __shared__ __align__(16) char lds[24576];   // X: [2][64][128B] @0; W: [2][64][64B] @16384

    const int tid  = threadIdx.x;
    const int nb   = blockIdx.x;   // 0..63 (64-row group)
    const int b    = blockIdx.y;   // 0..7
    const int inp  = blockIdx.z;   // 0..1
    const float* __restrict__ x = inp ? x2 : x1;
    const float* __restrict__ xbase = x + ((size_t)b * N_ + (size_t)nb * ROWS) * F_;

    const int lane = tid & 63;
    const int w    = tid >> 6;       // wave 0..3 = m-tile
    const int rsel = lane & 15;
    const int g    = lane >> 4;      // 0..3

    // per-block chunk-start stagger: spread concurrent k-offsets
    const int t0 = (nb ^ (b << 2) ^ (inp << 4)) & (NT - 1);

#define XOFF(buf) ((buf) * 8192)
#define WOFF(buf) (16384 + (buf) * 4096)

#define STAGE(t, buf)                                                          \
    do {                                                                       \
        const int f0_ = (t) * KC;                                              \
        _Pragma("unroll")                                                      \
        for (int j = 0; j < 2; ++j) {                                          \
            int ii = w * 2 + j;                                                \
            int r  = ii * 8 + (lane >> 3);                                     \
            int cg = (lane & 7) ^ (r & 7);                                     \
            load_lds16(xbase + (size_t)r * F_ + f0_ + cg * 4,                  \
                       lds + XOFF(buf) + ii * 1024);                           \
        }                                                                      \
        {                                                                      \
            int cls = w * 16 + (lane >> 2);                                    \
            int cg  = (lane & 3) ^ ((cls >> 1) & 3);                           \
            load_lds16(Wh + (size_t)cls * F_ + f0_ + cg * 8,                   \
                       lds + WOFF(buf) + w * 1024);                            \
        }                                                                      \
    } while (0)

#define COMPUTE(buf)                                                           \
    do {                                                                       \
        const char* xb = lds + XOFF(buf);                                      \
        const char* wb = lds + WOFF(buf);                                      \
        float4 xlo = *(const float4*)(xb + r_ * 128 + aswz0);                  \
        float4 xhi = *(const float4*)(xb + r_ * 128 + aswz1);                  \
        bhalf8 ah = cvt8(xlo, xhi);                                            \
        _Pragma("unroll")                                                      \
        for (int nt = 0; nt < 4; ++nt) {                                       \
            int cls = nt * 16 + rsel;                                          \
            bhalf8 bf = *(const bhalf8*)(wb + cls * 64 + ((g ^ ((cls >> 1) & 3)) * 16)); \
            acc[nt] = __builtin_amdgcn_mfma_f32_16x16x32_bf16(ah, bf, acc[nt], 0, 0, 0); \
        }                                                                      \
    } while (0)

    f32x4 acc[4];
    #pragma unroll
    for (int nt = 0; nt < 4; ++nt) acc[nt] = (f32x4){0.f, 0.f, 0.f, 0.f};

    const int r_    = w * 16 + rsel;          // local A row
    const int aswz0 = ((2 * g)     ^ (r_ & 7)) * 16;
    const int aswz1 = ((2 * g + 1) ^ (r_ & 7)) * 16;

    STAGE(t0, 0);
    __syncthreads();

    for (int t = 0; t < NT; ++t) {
        const int cur = t & 1;
        if (t + 1 < NT) STAGE((t0 + t + 1) & (NT - 1), cur ^ 1);
        COMPUTE(cur);
        __syncthreads();   // drains STAGE vmcnt; protects buffer reuse
    }

    // ---- per-wave top-3 per class. D layout: col=lane&15 (class), row=4g+r.
    float wv0[4], wv1[4], wv2[4]; int wi0[4], wi1[4], wi2[4];
    #pragma unroll
    for (int nt = 0; nt < 4; ++nt) {
        float v0 = -3.4e38f, v1 = -3.4e38f, v2 = -3.4e38f;
        int   i0 = 0x7fffffff, i1 = 0x7fffffff, i2 = 0x7fffffff;
        #pragma unroll
        for (int r = 0; r < 4; ++r) {
            int n = nb * ROWS + w * 16 + 4 * g + r;
            INSERT3(acc[nt][r], n);
        }
        #pragma unroll
        for (int d = 16; d <= 32; d <<= 1) {
            float u0 = __shfl_xor(v0, d), u1 = __shfl_xor(v1, d), u2 = __shfl_xor(v2, d);
            int   j0 = __shfl_xor(i0, d), j1 = __shfl_xor(i1, d), j2 = __shfl_xor(i2, d);
            INSERT3(u0, j0); INSERT3(u1, j1); INSERT3(u2, j2);
        }
        wv0[nt] = v0; wv1[nt] = v1; wv2[nt] = v2;
        wi0[nt] = i0; wi1[nt] = i1; wi2[nt] = i2;
    }

    __syncthreads();                 // safe to alias LDS now
    float* tv = (float*)lds;                   // [4][64][3] = 3 KiB
    int*   ti = (int*)(lds + 8192);            // [4][64][3] = 3 KiB
    if (lane < 16) {
        #pragma unroll
        for (int nt = 0; nt < 4; ++nt) {
            int c = nt * 16 + lane;
            tv[(w * C_ + c) * 3 + 0] = wv0[nt]; ti[(w * C_ + c) * 3 + 0] = wi0[nt];
            tv[(w * C_ + c) * 3 + 1] = wv1[nt]; ti[(w * C_ + c) * 3 + 1] = wi1[nt];
            tv[(w * C_ + c) * 3 + 2] = wv2[nt]; ti[(w * C_ + c) * 3 + 2] = wi2[nt];
        }
    }
    __syncthreads();

    // ---- block top-3 per class over 4 waves x 3, write partials
    if (tid < C_) {
        int c = tid;
        float v0 = -3.4e38f, v1 = -3.4e38f, v2 = -3.4e38f;
        int   i0 = 0x7fffffff, i1 = 0x7fffffff, i2 = 0x7fffffff;
        #pragma unroll
        for (int ww = 0; ww < 4; ++ww)
            #pragma unroll
            for (int k = 0; k < 3; ++k)
                INSERT3(tv[(ww * C_ + c) * 3 + k], ti[(ww * C_ + c) * 3 + k]);
        int blk = ((inp * B_ + b) * NBLK + nb);
        pv[(blk * C_ + c) * 3 + 0] = v0; pi[(blk * C_ + c) * 3 + 0] = i0;
        pv[(blk * C_ + c) * 3 + 1] = v1; pi[(blk * C_ + c) * 3 + 1] = i1;
        pv[(blk * C_ + c) * 3 + 2] = v2; pi[(blk * C_ + c) * 3 + 2] = i2;
    }
}

// K2: ONE WAVE per (inp,b,c). lane = row-block (64), each holds its top-3.
// Ballot-collect candidates within MARGIN of global max; exact fp32 dot
// rescue if >1 (lex tie-break: score desc, index asc); gather winning row.
__global__ __launch_bounds__(64) void select_gather_kernel(
    const float* __restrict__ x1, const float* __restrict__ x2,
    const float* __restrict__ W,
    const float* __restrict__ pv, const int* __restrict__ pi,
    float* __restrict__ out)
{
    const int c    = blockIdx.x;    // 0..63
    const int b    = blockIdx.y;    // 0..7
    const int inp  = blockIdx.z;    // 0..1
    const int lane = threadIdx.x;   // 0..63 = row-block

    const int blk  = ((inp * B_ + b) * NBLK + lane);
    const int base = (blk * C_ + c) * 3;
    const float v0 = pv[base + 0], v1 = pv[base + 1], v2 = pv[base + 2];
    const int   j0 = pi[base + 0], j1 = pi[base + 1], j2 = pi[base + 2];

    float m = v0;                       // entries sorted: v0 is block max
    #pragma unroll
    for (int d = 32; d; d >>= 1) m = fmaxf(m, __shfl_xor(m, d));
    const float thr = m - MARGIN;

    int cand[8]; int nc = 0;
    #pragma unroll
    for (int k = 0; k < 3; ++k) {
        float vk = k == 0 ? v0 : (k == 1 ? v1 : v2);
        int   jk = k == 0 ? j0 : (k == 1 ? j1 : j2);
        unsigned long long mask = __ballot(vk >= thr);
        while (mask) {
            int l = __ffsll(mask) - 1; mask &= mask - 1;
            int n = __shfl(jk, l);
            if (nc < 8) cand[nc++] = n;
        }
    }

    const float* __restrict__ x = inp ? x2 : x1;
    int winner;
    if (nc == 1) {
        winner = cand[0];
    } else {
        float bv = -3.4e38f; int bn = 0x7fffffff;
        const float4* wrow = (const float4*)(W + (size_t)c * F_) + lane * 4;
        for (int k = 0; k < nc; ++k) {
            int n = cand[k];
            const float4* xrow = (const float4*)(x + ((size_t)b * N_ + n) * F_) + lane * 4;
            float p = 0.f;
            #pragma unroll
            for (int q = 0; q < 4; ++q) {
                float4 xv = xrow[q], wq = wrow[q];
                p += xv.x * wq.x + xv.y * wq.y + xv.z * wq.z + xv.w * wq.w;
            }
            #pragma unroll
            for (int d = 32; d; d >>= 1) p += __shfl_xor(p, d);   // all lanes get sum
            if (p > bv || (p == bv && n < bn)) { bv = p; bn = n; }
        }
        winner = bn;
    }

    const float4* src = (const float4*)(x + ((size_t)b * N_ + winner) * F_);
    float4* dst = (float4*)(out + (((size_t)inp * B_ + b) * C_ + c) * F_);
    #pragma unroll
    for (int q = 0; q < 4; ++q) dst[lane + 64 * q] = src[lane + 64 * q];
}

extern "C" void kernel_launch(void* const* d_in, const int* in_sizes, int n_in,
                              void* d_out, int out_size, void* d_ws, size_t ws_size,
                              hipStream_t stream) {
    const float* x1 = (const float*)d_in[0];
    const float* x2 = (const float*)d_in[1];
    const float* W  = (const float*)d_in[2];
    // d_in[3] (bias) is constant per class -> cannot change the argmax. Skipped.

    // ws: Wh bf16 [64][1024] = 128 KiB | pv [1024][64][3] f32 = 768 KiB | pi = 768 KiB
    unsigned short* Wh = (unsigned short*)d_ws;
    float* pv = (float*)((char*)d_ws + (size_t)C_ * F_ * sizeof(unsigned short));
    int*   pi = (int*)((char*)pv + (size_t)2 * B_ * NBLK * C_ * 3 * sizeof(float));

    wconv_kernel<<<C_ * F_ / 1024, 256, 0, stream>>>(W, Wh);
    dim3 g1(NBLK, B_, 2);
    score_top_kernel<<<g1, 256, 0, stream>>>(x1, x2, Wh, pv, pi);
    dim3 g2(C_, B_, 2);
    select_gather_kernel<<<g2, 64, 0, stream>>>(x1, x2, W, pv, pi, (float*)d_out);
}

// Round 13
// 63.231 us; speedup vs baseline: 1.3463x; 1.0378x over previous
//
#include <hip/hip_runtime.h>

// Problem constants (reference: B=8, N=4096, F=1024, C=64)
#define B_   8
#define N_   4096
#define F_   1024
#define C_   64
#define ROWS 32          // rows per block
#define KC   64          // K (f) floats per chunk -> 256 B contiguous per row visit
#define NT   (F_ / KC)   // 16 chunks
#define NBLK (N_ / ROWS) // 128 row-blocks per (inp,b)
#define MARGIN 0.08f     // hi-only bf16 score error sigma ~6e-3; 0.08 ~ 10 sigma on diffs

typedef __attribute__((ext_vector_type(8))) short bhalf8;   // 8 bf16 (MFMA A/B frag)
typedef __attribute__((ext_vector_type(4))) float f32x4;    // MFMA C/D frag
typedef __attribute__((ext_vector_type(4))) unsigned short us4;

__device__ __forceinline__ unsigned short f2bf_rne(float x) {
    unsigned u = __builtin_bit_cast(unsigned, x);
    u += 0x7fffu + ((u >> 16) & 1u);          // round-to-nearest-even
    return (unsigned short)(u >> 16);
}
__device__ __forceinline__ bhalf8 cvt8(float4 a, float4 b) {
    bhalf8 r;
    r[0] = (short)f2bf_rne(a.x); r[1] = (short)f2bf_rne(a.y);
    r[2] = (short)f2bf_rne(a.z); r[3] = (short)f2bf_rne(a.w);
    r[4] = (short)f2bf_rne(b.x); r[5] = (short)f2bf_rne(b.y);
    r[6] = (short)f2bf_rne(b.z); r[7] = (short)f2bf_rne(b.w);
    return r;
}
// Direct global->LDS. LDS dest is wave-uniform base + lane*16; global src is
// per-lane (carries the bank pre-swizzle, permuting 16B granules WITHIN the
// row's 256B chunk so the DRAM footprint stays one contiguous 256B segment).
__device__ __forceinline__ void load_lds16(const void* g, void* l) {
    __builtin_amdgcn_global_load_lds(
        (const __attribute__((address_space(1))) unsigned int*)g,
        (__attribute__((address_space(3))) unsigned int*)l, 16, 0, 0);
}

#define LEXGT(a, ai, b, bi) ((a) > (b) || ((a) == (b) && (ai) < (bi)))
#define INSERT2(vv, nn)                                                        \
    do {                                                                       \
        float _v = (vv); int _n = (nn);                                        \
        if (LEXGT(_v, _n, v0, i0)) { v1=v0; i1=i0; v0=_v; i0=_n; }             \
        else if (LEXGT(_v, _n, v1, i1)) { v1=_v; i1=_n; }                      \
    } while (0)

// K0: convert W (fp32 [64][1024]) to bf16 (hi only) in workspace.
__global__ __launch_bounds__(256) void wconv_kernel(
    const float* __restrict__ W, unsigned short* __restrict__ Wh)
{
    int i = blockIdx.x * 256 + threadIdx.x;        // 16384 float4s total
    float4 v = ((const float4*)W)[i];
    us4 hh;
    hh[0] = f2bf_rne(v.x); hh[1] = f2bf_rne(v.y);
    hh[2] = f2bf_rne(v.z); hh[3] = f2bf_rne(v.w);
    ((us4*)Wh)[i] = hh;
}

// K1: hi-only bf16 MFMA scores. R7 2-phase global_load_lds pipeline with
// 2x DRAM page locality: KC=64 -> each X stage instruction reads 4 rows x
// 256 B CONTIGUOUS (vs 8 rows x 128 B before); page visits per row halve.
// 256 thr = 4 waves (wm = w&1: 16 rows; wn = w>>1: 32 classes), ROWS=32,
// 32 KiB LDS -> 5 blocks/CU. Per-block k-chunk stagger kept (free).
__global__ __launch_bounds__(256, 5) void score_top_kernel(
    const float* __restrict__ x1, const float* __restrict__ x2,
    const unsigned short* __restrict__ Wh,
    float* __restrict__ pv, int* __restrict__ pi)
{
    __shared__ __align__(16) char lds[32768];   // X: [2][32][256B] @0; W: [2][64][128B] @16384

    const int tid  = threadIdx.x;
    const int nb   = blockIdx.x;   // 0..127 (32-row group)
    const int b    = blockIdx.y;   // 0..7
    const int inp  = blockIdx.z;   // 0..1
    const float* __restrict__ x = inp ? x2 : x1;
    const char* __restrict__ xbase = (const char*)(x + ((size_t)b * N_ + (size_t)nb * ROWS) * F_);
    const char* __restrict__ wbase = (const char*)Wh;

    const int lane = tid & 63;
    const int w    = tid >> 6;       // wave 0..3
    const int wm   = w & 1;          // m-tile (16 rows)
    const int wn   = w >> 1;         // n-half (32 classes)
    const int rsel = lane & 15;
    const int g    = lane >> 4;      // 0..3

    const int t0 = (nb ^ (b << 2) ^ (inp << 3)) & (NT - 1);   // chunk stagger

#define XOFF(buf) ((buf) * 8192)
#define WOFF(buf) (16384 + (buf) * 8192)

#define STAGE(t, buf)                                                          \
    do {                                                                       \
        const int tb = (t);                                                    \
        _Pragma("unroll")                                                      \
        for (int j = 0; j < 2; ++j) {        /* X: 4 rows x 256B per inst */   \
            int rb = w * 8 + j * 4;                                            \
            int r  = rb + (lane >> 4);                                         \
            int off = ((lane & 15) * 16) ^ ((r & 7) << 4);                     \
            load_lds16(xbase + (size_t)r * 4096 + tb * 256 + off,              \
                       lds + XOFF(buf) + rb * 256);                            \
        }                                                                      \
        _Pragma("unroll")                                                      \
        for (int j = 0; j < 2; ++j) {        /* W: 8 cls x 128B per inst */    \
            int ib  = w * 2 + j;                                               \
            int cls = ib * 8 + (lane >> 3);                                    \
            int off = ((lane & 7) * 16) ^ ((cls & 7) << 4);                    \
            load_lds16(wbase + (size_t)cls * 2048 + tb * 128 + off,            \
                       lds + WOFF(buf) + ib * 1024);                           \
        }                                                                      \
    } while (0)

#define COMPUTE(buf)                                                           \
    do {                                                                       \
        const char* xb = lds + XOFF(buf);                                      \
        const char* wb = lds + WOFF(buf);                                      \
        _Pragma("unroll")                                                      \
        for (int ks = 0; ks < 2; ++ks) {                                       \
            float4 xlo = *(const float4*)(xb + row_ * 256 + ((ks * 128 + g * 32)      ^ aswz)); \
            float4 xhi = *(const float4*)(xb + row_ * 256 + ((ks * 128 + g * 32 + 16) ^ aswz)); \
            bhalf8 ah = cvt8(xlo, xhi);                                        \
            _Pragma("unroll")                                                  \
            for (int ntl = 0; ntl < 2; ++ntl) {                                \
                int cls = wn * 32 + ntl * 16 + rsel;                           \
                bhalf8 bf = *(const bhalf8*)(wb + cls * 128 + ((ks * 64 + g * 16) ^ aswz)); \
                acc[ntl] = __builtin_amdgcn_mfma_f32_16x16x32_bf16(ah, bf, acc[ntl], 0, 0, 0); \
            }                                                                  \
        }                                                                      \
    } while (0)

    f32x4 acc[2];
    acc[0] = (f32x4){0.f, 0.f, 0.f, 0.f};
    acc[1] = (f32x4){0.f, 0.f, 0.f, 0.f};

    const int row_ = wm * 16 + rsel;          // local A row (0..31)
    const int aswz = (rsel & 7) << 4;         // row&7 == cls&7 == rsel&7

    STAGE(t0, 0);
    __syncthreads();

    for (int t = 0; t < NT; ++t) {
        const int cur = t & 1;
        if (t + 1 < NT) STAGE((t0 + t + 1) & (NT - 1), cur ^ 1);
        COMPUTE(cur);
        __syncthreads();   // drains STAGE vmcnt; protects buffer reuse
    }

    // ---- per-wave top-2 per class. D layout: col=rsel (class), row=4g+r.
    float wv0[2], wv1[2]; int wi0[2], wi1[2];
    #pragma unroll
    for (int ntl = 0; ntl < 2; ++ntl) {
        float v0 = -3.4e38f, v1 = -3.4e38f;
        int   i0 = 0x7fffffff, i1 = 0x7fffffff;
        #pragma unroll
        for (int r = 0; r < 4; ++r) {
            int n = nb * ROWS + wm * 16 + 4 * g + r;
            INSERT2(acc[ntl][r], n);
        }
        #pragma unroll
        for (int d = 16; d <= 32; d <<= 1) {
            float u0 = __shfl_xor(v0, d), u1 = __shfl_xor(v1, d);
            int   j0 = __shfl_xor(i0, d), j1 = __shfl_xor(i1, d);
            INSERT2(u0, j0); INSERT2(u1, j1);
        }
        wv0[ntl] = v0; wv1[ntl] = v1;
        wi0[ntl] = i0; wi1[ntl] = i1;
    }

    __syncthreads();                 // done with X/W buffers -> safe to alias
    float* tv = (float*)lds;                   // [2 wm][64][2] = 1 KiB
    int*   ti = (int*)(lds + 4096);            // [2 wm][64][2] = 1 KiB
    if (lane < 16) {
        #pragma unroll
        for (int ntl = 0; ntl < 2; ++ntl) {
            int c = wn * 32 + ntl * 16 + lane;
            tv[(wm * C_ + c) * 2 + 0] = wv0[ntl]; ti[(wm * C_ + c) * 2 + 0] = wi0[ntl];
            tv[(wm * C_ + c) * 2 + 1] = wv1[ntl]; ti[(wm * C_ + c) * 2 + 1] = wi1[ntl];
        }
    }
    __syncthreads();

    // ---- block top-2 per class over 2 wm-waves x 2, write partials
    if (tid < C_) {
        int c = tid;
        float v0 = -3.4e38f, v1 = -3.4e38f;
        int   i0 = 0x7fffffff, i1 = 0x7fffffff;
        #pragma unroll
        for (int ww = 0; ww < 2; ++ww)
            #pragma unroll
            for (int k = 0; k < 2; ++k)
                INSERT2(tv[(ww * C_ + c) * 2 + k], ti[(ww * C_ + c) * 2 + k]);
        int blk = ((inp * B_ + b) * NBLK + nb);
        pv[(blk * C_ + c) * 2 + 0] = v0; pi[(blk * C_ + c) * 2 + 0] = i0;
        pv[(blk * C_ + c) * 2 + 1] = v1; pi[(blk * C_ + c) * 2 + 1] = i1;
    }
}

// K2: ONE WAVE per (inp,b,c). 256 entries (128 blocks x top-2) = 4 per lane.
// Ballot-collect candidates within MARGIN of global max; exact fp32 dot
// rescue if >1 (lex tie-break: score desc, index asc); gather winning row.
__global__ __launch_bounds__(64) void select_gather_kernel(
    const float* __restrict__ x1, const float* __restrict__ x2,
    const float* __restrict__ W,
    const float* __restrict__ pv, const int* __restrict__ pi,
    float* __restrict__ out)
{
    const int c    = blockIdx.x;    // 0..63
    const int b    = blockIdx.y;    // 0..7
    const int inp  = blockIdx.z;    // 0..1
    const int lane = threadIdx.x;   // 0..63; handles blocks 2*lane, 2*lane+1

    float v[4]; int id[4];
    #pragma unroll
    for (int j = 0; j < 2; ++j) {
        int blk = ((inp * B_ + b) * NBLK + lane * 2 + j);
        #pragma unroll
        for (int k = 0; k < 2; ++k) {
            int off = (blk * C_ + c) * 2 + k;
            v[j * 2 + k] = pv[off]; id[j * 2 + k] = pi[off];
        }
    }

    float m = fmaxf(fmaxf(v[0], v[1]), fmaxf(v[2], v[3]));
    #pragma unroll
    for (int d = 32; d; d >>= 1) m = fmaxf(m, __shfl_xor(m, d));
    const float thr = m - MARGIN;

    int cand[8]; int nc = 0;
    #pragma unroll
    for (int k = 0; k < 4; ++k) {
        unsigned long long mask = __ballot(v[k] >= thr);
        while (mask) {
            int l = __ffsll(mask) - 1; mask &= mask - 1;
            int n = __shfl(id[k], l);
            if (nc < 8) cand[nc++] = n;
        }
    }

    const float* __restrict__ x = inp ? x2 : x1;
    int winner;
    if (nc == 1) {
        winner = cand[0];
    } else {
        float bv = -3.4e38f; int bn = 0x7fffffff;
        const float4* wrow = (const float4*)(W + (size_t)c * F_) + lane * 4;
        for (int k = 0; k < nc; ++k) {
            int n = cand[k];
            const float4* xrow = (const float4*)(x + ((size_t)b * N_ + n) * F_) + lane * 4;
            float p = 0.f;
            #pragma unroll
            for (int q = 0; q < 4; ++q) {
                float4 xv = xrow[q], wq = wrow[q];
                p += xv.x * wq.x + xv.y * wq.y + xv.z * wq.z + xv.w * wq.w;
            }
            #pragma unroll
            for (int d = 32; d; d >>= 1) p += __shfl_xor(p, d);   // all lanes get sum
            if (p > bv || (p == bv && n < bn)) { bv = p; bn = n; }
        }
        winner = bn;
    }

    const float4* src = (const float4*)(x + ((size_t)b * N_ + winner) * F_);
    float4* dst = (float4*)(out + (((size_t)inp * B_ + b) * C_ + c) * F_);
    #pragma unroll
    for (int q = 0; q < 4; ++q) dst[lane + 64 * q] = src[lane + 64 * q];
}

extern "C" void kernel_launch(void* const* d_in, const int* in_sizes, int n_in,
                              void* d_out, int out_size, void* d_ws, size_t ws_size,
                              hipStream_t stream) {
    const float* x1 = (const float*)d_in[0];
    const float* x2 = (const float*)d_in[1];
    const float* W  = (const float*)d_in[2];
    // d_in[3] (bias) is constant per class -> cannot change the argmax. Skipped.

    // ws: Wh bf16 [64][1024] = 128 KiB | pv [2048][64][2] f32 = 1 MiB | pi = 1 MiB
    unsigned short* Wh = (unsigned short*)d_ws;
    float* pv = (float*)((char*)d_ws + (size_t)C_ * F_ * sizeof(unsigned short));
    int*   pi = (int*)((char*)pv + (size_t)2 * B_ * NBLK * C_ * 2 * sizeof(float));

    wconv_kernel<<<C_ * F_ / 1024, 256, 0, stream>>>(W, Wh);
    dim3 g1(NBLK, B_, 2);
    score_top_kernel<<<g1, 256, 0, stream>>>(x1, x2, Wh, pv, pi);
    dim3 g2(C_, B_, 2);
    select_gather_kernel<<<g2, 64, 0, stream>>>(x1, x2, W, pv, pi, (float*)d_out);
}